// Round 7
// baseline (906.509 us; speedup 1.0000x reference)
//
#include <hip/hip_runtime.h>
#include <stdint.h>

// ---------- types / helpers ----------
typedef __attribute__((ext_vector_type(8))) short bf16x8;   // 8 bf16 in 4 VGPRs
typedef __attribute__((ext_vector_type(4))) float f32x4;

static __device__ __forceinline__ short f2bf(float f) {
  uint32_t u = __builtin_bit_cast(uint32_t, f);
  u += 0x7fffu + ((u >> 16) & 1u);          // round-to-nearest-even
  return (short)(u >> 16);
}

static __device__ __forceinline__ void gload_lds16(const void* g, void* l) {
  __builtin_amdgcn_global_load_lds((const __attribute__((address_space(1))) void*)g,
                                   (__attribute__((address_space(3))) void*)l, 16, 0, 0);
}

#define GFENCE asm volatile("" ::: "memory")

// ---------- x transpose: (B,C,T,H,W) f32 -> xb[n][c] bf16, n = b*16384 + p ----------
__global__ __launch_bounds__(256) void transpose_x_k(const float* __restrict__ x,
                                                     short* __restrict__ xb) {
  __shared__ float t[64][65];
  const int pt = blockIdx.x, ct = blockIdx.y, b = blockIdx.z;
  const int tid = threadIdx.x;
#pragma unroll
  for (int i = 0; i < 16; i++) {
    int cc = i * 4 + (tid >> 6);
    int pp = tid & 63;
    t[cc][pp] = x[(size_t)(b * 512 + ct * 64 + cc) * 16384 + pt * 64 + pp];
  }
  __syncthreads();
#pragma unroll
  for (int i = 0; i < 2; i++) {
    int seg = i * 256 + tid;
    int pw = seg >> 3, c8 = seg & 7;
    short tmp[8];
#pragma unroll
    for (int k = 0; k < 8; k++) tmp[k] = f2bf(t[c8 * 8 + k][pw]);
    *(uint4*)&xb[(size_t)(b * 16384 + pt * 64 + pw) * 512 + ct * 64 + c8 * 8] =
        *(const uint4*)tmp;
  }
}

// ---------- weight transpose+pack: (512x512 f32 [k][n]) -> fragment-major bf16 ----------
// unit (g, t, l) holds R[g*16 + (l&15)][t*32 + (l>>4)*8 .. +8] where R = src^T ([n][k]).
// dst unit offset = (nt*4+g')*gp + (t0 + kt*2+t')*64 + l   (unit = 8 shorts = 16 B)
struct WPtrs {
  const float* src[12];
  short* dst[12];
  int t0[12];   // k-tile offset within resident K
  int gp[12];   // group pitch in units (= NT_resident * 64)
};

__global__ __launch_bounds__(256) void transpose_pack_k(WPtrs P) {
  __shared__ float t[64][65];
  const int kt = blockIdx.x, nt = blockIdx.y, z = blockIdx.z;
  const float* src = P.src[z];
  short* dst = P.dst[z];
  const int tid = threadIdx.x;
#pragma unroll
  for (int i = 0; i < 16; i++) {
    int kk = i * 4 + (tid >> 6);
    int nn = tid & 63;
    t[kk][nn] = src[(size_t)(kt * 64 + kk) * 512 + nt * 64 + nn];
  }
  __syncthreads();
#pragma unroll
  for (int half = 0; half < 2; half++) {
    int u = half * 256 + tid;
    int gl = u >> 7;           // 0..3 local group
    int tp = (u >> 6) & 1;     // 0..1 local k-tile
    int l = u & 63;
    short tmp[8];
#pragma unroll
    for (int j = 0; j < 8; j++)
      tmp[j] = f2bf(t[tp * 32 + (l >> 4) * 8 + j][gl * 16 + (l & 15)]);
    size_t unit = (size_t)(nt * 4 + gl) * P.gp[z] +
                  (size_t)(P.t0[z] + kt * 2 + tp) * 64 + l;
    *(uint4*)&dst[unit * 8] = *(const uint4*)tmp;
  }
}

__global__ void bsum_k(const float* a, const float* b, const float* c, float* o) {
  int i = blockIdx.x * 256 + threadIdx.x;
  if (i < 512) o[i] = a[i] + b[i] + c[i];
}

// ---------- 128x128 GEMM, resident-operand-in-regs: D = A * B^T ----------
// Streamed matrix S staged in LDS (4 bufs x 8 KB = 32 KB, stage depth 3, swizzled
// chunks as round-6, 0 bank conflicts). Resident matrix R read per K-tile as 4
// coalesced global_load_dwordx4 from the packed frag-major buffer (double-buffered
// rfA/rfB, prefetched 1 tile ahead). vmcnt ledger (per thread: stage=2, rf=4):
//   prologue A0,rf0,A1,A2 -> iter0 wait 4; steady queue [A(t+1),rf(t),A(t+2)] ->
//   wait 2; tail waits 0,0. LDS traffic halves vs round-6 -> MFMA becomes floor.
// MODE 0 (QKV): streamed = A-side (xb rows), resident = B-side (weights);
//               D bf16 [M][ldd].
// MODE 1 (fc):  streamed = B-side (ob rows), resident = A-side (fc weights);
//               D f32 out (B,C,THW) = v + bsum[c].
template <int MODE>
__global__ __launch_bounds__(256, 3) void gemm128r_k(const short* __restrict__ S,
                                                     int ldS,
                                                     const short* __restrict__ Rp,
                                                     void* __restrict__ Dp, int K,
                                                     int ldd,
                                                     const float* __restrict__ bsum,
                                                     int GN) {
  __shared__ char smem[32768];
  const int tid = threadIdx.x;
  const int lane = tid & 63, wave = tid >> 6;
  const int wm = (wave >> 1) << 6, wn = (wave & 1) << 6;
  const int r4 = lane & 15, kl = lane >> 4;

  // bijective XCD swizzle (gridDim.x % 8 == 0)
  int bid = blockIdx.x;
  const int cpx = gridDim.x >> 3;
  bid = (bid & 7) * cpx + (bid >> 3);
  int bm, bn;
  if constexpr (MODE == 0) {
    bn = bid % GN;
    bm = bid / GN;
  } else {
    bm = bid & 3;
    bn = bid >> 2;
  }

  const int NT = K >> 5;  // BK = 32; resident K == streamed K
  const int wS = (MODE == 0) ? wm : wn;   // streamed-side wave offset
  const int wR = (MODE == 0) ? wn : wm;   // resident-side wave offset
  const int bS = (MODE == 0) ? bm : bn;   // streamed tile idx
  const int bR = (MODE == 0) ? bn : bm;   // resident tile idx

  // streamed staging (round-6 proven: swizzled global chunk, linear LDS dest)
  const int schk = (lane & 3) ^ ((lane >> 3) & 3);
  const short* gS0 =
      S + (size_t)(bS * 128 + wave * 32 + (lane >> 2)) * ldS + schk * 8;

  // resident packed bases (lane folded in); per-tile step = 512 shorts (1 KB)
  const int g0 = bR * 8 + (wR >> 4);
  const short* rb0 = Rp + ((size_t)(g0 + 0) * NT * 64 + lane) * 8;
  const short* rb1 = Rp + ((size_t)(g0 + 1) * NT * 64 + lane) * 8;
  const short* rb2 = Rp + ((size_t)(g0 + 2) * NT * 64 + lane) * 8;
  const short* rb3 = Rp + ((size_t)(g0 + 3) * NT * 64 + lane) * 8;

  // LDS fragment read offset (swizzle-consistent with staging)
  const int kls = kl ^ ((r4 >> 1) & 3);
  const int loff = (wS + r4) * 64 + kls * 16;

  f32x4 acc[4][4];
#pragma unroll
  for (int i = 0; i < 4; ++i)
#pragma unroll
    for (int j = 0; j < 4; ++j) acc[i][j] = (f32x4){0.f, 0.f, 0.f, 0.f};
  bf16x8 lf[4], rfA[4], rfB[4];

  auto stage = [&](int tt) {
    char* d = smem + (tt & 3) * 8192 + wave * 2048;
    gload_lds16(gS0 + (size_t)tt * 32, d);
    gload_lds16(gS0 + (size_t)16 * ldS + (size_t)tt * 32, d + 1024);
  };

#define MFMA_STEP(CUR)                                                         \
  do {                                                                         \
    __builtin_amdgcn_s_setprio(1);                                             \
    _Pragma("unroll") for (int mi = 0; mi < 4; ++mi)                           \
        _Pragma("unroll") for (int ni = 0; ni < 4; ++ni) {                     \
      if constexpr (MODE == 0)                                                 \
        acc[mi][ni] = __builtin_amdgcn_mfma_f32_16x16x32_bf16(                 \
            lf[mi], CUR[ni], acc[mi][ni], 0, 0, 0);                            \
      else                                                                     \
        acc[mi][ni] = __builtin_amdgcn_mfma_f32_16x16x32_bf16(                 \
            CUR[mi], lf[ni], acc[mi][ni], 0, 0, 0);                            \
    }                                                                          \
    __builtin_amdgcn_s_setprio(0);                                             \
  } while (0)

#define TILEV(tq, WAIT, CUR, NXT, DOSTAGE, DOPF)                               \
  do {                                                                         \
    asm volatile("s_waitcnt vmcnt(" WAIT ")" ::: "memory");                    \
    __builtin_amdgcn_s_barrier();                                              \
    GFENCE;                                                                    \
    if (DOPF) {                                                                \
      NXT[0] = *(const bf16x8*)(rb0 + ((tq) + 1) * 512);                       \
      NXT[1] = *(const bf16x8*)(rb1 + ((tq) + 1) * 512);                       \
      NXT[2] = *(const bf16x8*)(rb2 + ((tq) + 1) * 512);                       \
      NXT[3] = *(const bf16x8*)(rb3 + ((tq) + 1) * 512);                       \
    }                                                                          \
    GFENCE;                                                                    \
    {                                                                          \
      const char* bp = smem + ((tq) & 3) * 8192;                               \
      _Pragma("unroll") for (int i = 0; i < 4; ++i) lf[i] =                    \
          *(const bf16x8*)(bp + loff + i * 1024);                              \
    }                                                                          \
    MFMA_STEP(CUR);                                                            \
    GFENCE;                                                                    \
    __builtin_amdgcn_s_barrier();                                              \
    GFENCE;                                                                    \
    if (DOSTAGE) stage((tq) + 3);                                              \
  } while (0)

  // prologue (order matters for the vmcnt ledger): A0, rf0, A1, A2
  stage(0);
  GFENCE;
  rfA[0] = *(const bf16x8*)rb0;
  rfA[1] = *(const bf16x8*)rb1;
  rfA[2] = *(const bf16x8*)rb2;
  rfA[3] = *(const bf16x8*)rb3;
  GFENCE;
  stage(1);
  stage(2);

  TILEV(0, "4", rfA, rfB, 1, 1);
  TILEV(1, "2", rfB, rfA, 1, 1);
  for (int t = 2; t + 4 <= NT; t += 2) {
    TILEV(t, "2", rfA, rfB, 1, 1);
    TILEV(t + 1, "2", rfB, rfA, (t + 1 <= NT - 4), 1);
  }
  TILEV(NT - 2, "0", rfA, rfB, 0, 1);
  TILEV(NT - 1, "0", rfB, rfA, 0, 0);

#undef TILEV
#undef MFMA_STEP

  // ---- epilogue: C/D layout col=lane&15, row=kl*4+reg
  const int m0 = wm + kl * 4;
  const int n0 = wn + r4;
  if (MODE == 0) {
    short* D = (short*)Dp;
#pragma unroll
    for (int mi = 0; mi < 4; ++mi)
#pragma unroll
      for (int ni = 0; ni < 4; ++ni)
#pragma unroll
        for (int r = 0; r < 4; ++r) {
          int row = bm * 128 + m0 + mi * 16 + r;
          int col = bn * 128 + n0 + ni * 16;
          D[(size_t)row * ldd + col] = f2bf(acc[mi][ni][r]);
        }
  } else {
    float* D = (float*)Dp + (size_t)((bn * 128) >> 14) * 8388608;
#pragma unroll
    for (int mi = 0; mi < 4; ++mi)
#pragma unroll
      for (int ni = 0; ni < 4; ++ni)
#pragma unroll
        for (int r = 0; r < 4; ++r) {
          int c = bm * 128 + m0 + mi * 16 + r;          // channel (M dim)
          int n = (bn * 128 + n0 + ni * 16) & 16383;    // spatial within batch
          D[(size_t)c * 16384 + n] = acc[mi][ni][r] + bsum[c];
        }
  }
}

// ---------- axial attention: one block per (sequence, head) ----------
// qkv: [n][1536] bf16 (Q|K|V each 512); o: [n][ostride] bf16 at column obase
template <int L>
__global__ __launch_bounds__(256) void attn_k(const short* __restrict__ qkv,
                                              short* __restrict__ o, int Adiv, int Bmul,
                                              int Cmul, int stride, int obase,
                                              int ostride) {
  constexpr int R = 256 / L;          // threads per row
  constexpr int SPT = (L * L) / 256;  // scores per thread
  constexpr int OPT = 64 / R;         // outputs per thread
  __shared__ short Ks[L][72];
  __shared__ short Vs[L][72];
  __shared__ short Qs[L][72];
  __shared__ float att[L][L + 1];
  const int tid = threadIdx.x;
  const int blk = blockIdx.x;
  const int s = blk >> 3, head = blk & 7;
  const int base = (s / Adiv) * Bmul + (s % Adiv) * Cmul;

  for (int idx = tid; idx < L * 8 * 3; idx += 256) {
    int part = idx / (L * 8);
    int rem = idx - part * (L * 8);
    int row = rem >> 3, seg = rem & 7;
    int n = base + row * stride;
    uint4 v = *(const uint4*)&qkv[(size_t)n * 1536 + part * 512 + head * 64 + seg * 8];
    short* dst = (part == 0 ? &Qs[row][0] : part == 1 ? &Ks[row][0] : &Vs[row][0]);
    *(uint4*)(dst + seg * 8) = v;
  }
  __syncthreads();

  const int l = tid / R, r = tid % R;
  float q[64];
#pragma unroll
  for (int w = 0; w < 8; w++) {
    uint4 u = *(const uint4*)&Qs[l][w * 8];
    uint32_t arr[4] = {u.x, u.y, u.z, u.w};
#pragma unroll
    for (int p = 0; p < 4; p++) {
      q[w * 8 + p * 2] = __builtin_bit_cast(float, arr[p] << 16);
      q[w * 8 + p * 2 + 1] = __builtin_bit_cast(float, arr[p] & 0xffff0000u);
    }
  }
  float sc[SPT];
#pragma unroll
  for (int jj = 0; jj < SPT; jj++) {
    int j = jj * R + r;
    float a0 = 0.f;
#pragma unroll
    for (int w = 0; w < 8; w++) {
      uint4 u = *(const uint4*)&Ks[j][w * 8];
      uint32_t arr[4] = {u.x, u.y, u.z, u.w};
#pragma unroll
      for (int p = 0; p < 4; p++) {
        a0 += q[w * 8 + p * 2] * __builtin_bit_cast(float, arr[p] << 16);
        a0 += q[w * 8 + p * 2 + 1] * __builtin_bit_cast(float, arr[p] & 0xffff0000u);
      }
    }
    sc[jj] = a0 * 0.125f;  // 1/sqrt(64)
  }
  float mx = sc[0];
#pragma unroll
  for (int jj = 1; jj < SPT; jj++) mx = fmaxf(mx, sc[jj]);
#pragma unroll
  for (int d = 1; d < R; d <<= 1) mx = fmaxf(mx, __shfl_xor(mx, d));
  float p_[SPT];
  float sum = 0.f;
#pragma unroll
  for (int jj = 0; jj < SPT; jj++) {
    p_[jj] = __expf(sc[jj] - mx);
    sum += p_[jj];
  }
#pragma unroll
  for (int d = 1; d < R; d <<= 1) sum += __shfl_xor(sum, d);
  float inv = 1.0f / sum;
#pragma unroll
  for (int jj = 0; jj < SPT; jj++) att[l][jj * R + r] = p_[jj] * inv;
  __syncthreads();

  float oa[OPT] = {};
#pragma unroll 4
  for (int j = 0; j < L; j++) {
    float a = att[l][j];
    if constexpr (OPT == 8) {
      uint4 u = *(const uint4*)&Vs[j][r * 8];
      uint32_t arr[4] = {u.x, u.y, u.z, u.w};
#pragma unroll
      for (int p = 0; p < 4; p++) {
        oa[p * 2] += a * __builtin_bit_cast(float, arr[p] << 16);
        oa[p * 2 + 1] += a * __builtin_bit_cast(float, arr[p] & 0xffff0000u);
      }
    } else {
      uint2 u = *(const uint2*)&Vs[j][r * 4];
      uint32_t arr[2] = {u.x, u.y};
#pragma unroll
      for (int p = 0; p < 2; p++) {
        oa[p * 2] += a * __builtin_bit_cast(float, arr[p] << 16);
        oa[p * 2 + 1] += a * __builtin_bit_cast(float, arr[p] & 0xffff0000u);
      }
    }
  }
  short tmp[OPT];
#pragma unroll
  for (int i = 0; i < OPT; i++) tmp[i] = f2bf(oa[i]);
  int n = base + l * stride;
  if constexpr (OPT == 8)
    *(uint4*)&o[(size_t)n * ostride + obase + head * 64 + r * 8] = *(const uint4*)tmp;
  else
    *(uint2*)&o[(size_t)n * ostride + obase + head * 64 + r * 4] = *(const uint2*)tmp;
}

// ---------- launch ----------
extern "C" void kernel_launch(void* const* d_in, const int* in_sizes, int n_in,
                              void* d_out, int out_size, void* d_ws, size_t ws_size,
                              hipStream_t stream) {
  const float* x = (const float*)d_in[0];
  const float* wq[3];
  const float* wk[3];
  const float* wv[3];
  const float* fc[3];
  const float* fb[3];
  for (int a = 0; a < 3; a++) {
    wq[a] = (const float*)d_in[1 + a * 5];
    wk[a] = (const float*)d_in[2 + a * 5];
    wv[a] = (const float*)d_in[3 + a * 5];
    fc[a] = (const float*)d_in[4 + a * 5];
    fb[a] = (const float*)d_in[5 + a * 5];
  }
  char* ws = (char*)d_ws;
  short* xb = (short*)(ws);                      //  67,108,864 B
  short* qkv = (short*)(ws + 67108864);          // 201,326,592 B
  short* wqkvp = (short*)(ws + 268435456);       //   4,718,592 B (3 axes x 96 grp x 16 kt)
  short* fcp = (short*)(ws + 273154048);         //   1,572,864 B (32 grp x 48 kt)
  float* bsum = (float*)(ws + 274726912);        //       2,048 B
  short* ob = (short*)(ws + 274728960);          // 201,326,592 B (65536 x 1536)
  float* out = (float*)d_out;

  WPtrs P;
  for (int a = 0; a < 3; a++) {
    const float* srcs[4] = {wq[a], wk[a], wv[a], fc[a]};
    for (int w = 0; w < 4; w++) {
      int z = a * 4 + w;
      P.src[z] = srcs[w];
      if (w < 3) {
        P.dst[z] = wqkvp + ((size_t)a * 98304 + (size_t)w * 32768) * 8;
        P.t0[z] = 0;
        P.gp[z] = 1024;   // NT=16 * 64
      } else {
        P.dst[z] = fcp;
        P.t0[z] = a * 16;
        P.gp[z] = 3072;   // NT=48 * 64
      }
    }
  }
  transpose_pack_k<<<dim3(8, 8, 12), 256, 0, stream>>>(P);
  bsum_k<<<dim3(2), 256, 0, stream>>>(fb[0], fb[1], fb[2], bsum);
  transpose_x_k<<<dim3(256, 8, 4), 256, 0, stream>>>(x, xb);

  // per-axis attention geometry: base = (s/Adiv)*Bmul + (s%Adiv)*Cmul, rows step `stride`
  const int Ad[3] = {1, 32, 1024};
  const int Bm_[3] = {32, 1024, 16384};
  const int Cm[3] = {0, 1, 1};
  const int St[3] = {1, 32, 1024};
  const int Ls[3] = {32, 32, 16};

  for (int a = 0; a < 3; a++) {
    // QKV: M=65536 (512 bm tiles), N=1536 (12 bn tiles), K=512 (NT=16)
    gemm128r_k<0><<<dim3(6144), 256, 0, stream>>>(
        xb, 512, wqkvp + (size_t)a * 98304 * 8, (void*)qkv, 512, 1536, nullptr, 12);
    if (Ls[a] == 32)
      attn_k<32><<<dim3(2048 * 8), 256, 0, stream>>>(qkv, ob, Ad[a], Bm_[a], Cm[a],
                                                     St[a], a * 512, 1536);
    else
      attn_k<16><<<dim3(4096 * 8), 256, 0, stream>>>(qkv, ob, Ad[a], Bm_[a], Cm[a],
                                                     St[a], a * 512, 1536);
  }
  // fused fc: out[c][n] = sum_k ob[n][k] * fcp-frags[c][k] + bsum[c]
  // M=512 (4 resident tiles), N=65536 (512 streamed tiles), K=1536 (NT=48)
  gemm128r_k<1><<<dim3(2048), 256, 0, stream>>>(ob, 1536, fcp, (void*)out, 1536, 0,
                                                bsum, 0);
}